// Round 1
// baseline (443.081 us; speedup 1.0000x reference)
//
#include <hip/hip_runtime.h>

#define N_NODES 50000
#define N_EDGES 800000

// ws layout (in floats):
//  [0, 400000)        esr[node][8] = {es0,es1,es2,cnt_s, er0,er1,er2,cnt_r}
//  [400000, 404096)   consts[k][32]: 0..15 M[j][k] (=W_en@W1a), 16..18 A[j][k] (=W_ee@W1b),
//                     19..21 B[j][k] (=W_ee@W1c), 22 cvec[k], 23 a0[k], 24 b0[k],
//                     25 w2dn[k] (=W2@W_dn), 26..27 pad (zeroed)
//  [404096, 404104)   scalars: {c, ce, wde0, wde1, wde2, pad...}
#define ESR_OFF    0
#define CONSTS_OFF 400000
#define SCAL_OFF   404096

__global__ void precompute_kernel(
    const float* __restrict__ g,      // globals_ [8]
    const float* __restrict__ W_en,   // [16][128]
    const float* __restrict__ b_en,   // [128]
    const float* __restrict__ W_ee,   // [3][128]
    const float* __restrict__ b_ee,   // [128]
    const float* __restrict__ W1,     // [392][128]
    const float* __restrict__ b1,     // [128]
    const float* __restrict__ W2,     // [128][128]
    const float* __restrict__ b2,     // [128]
    const float* __restrict__ W_dn,   // [128]
    const float* __restrict__ b_dn,   // [1]
    const float* __restrict__ W_de,   // [128]
    const float* __restrict__ b_de,   // [1]
    float* __restrict__ ws)
{
    const int s = blockIdx.x;   // which slot/row we compute
    const int k = threadIdx.x;  // latent column 0..127
    float* consts = ws + CONSTS_OFF;
    float* scal   = ws + SCAL_OFF;

    if (s < 16) {
        // M[s][k] = sum_l W_en[s,l] * W1[l,k]
        float acc = 0.f;
        for (int l = 0; l < 128; ++l)
            acc += W_en[s * 128 + l] * W1[l * 128 + k];
        consts[k * 32 + s] = acc;
    } else if (s < 19) {
        // A[j][k] = sum_l W_ee[j,l] * W1[128+l, k]
        const int j = s - 16;
        float acc = 0.f;
        for (int l = 0; l < 128; ++l)
            acc += W_ee[j * 128 + l] * W1[(128 + l) * 128 + k];
        consts[k * 32 + s] = acc;
    } else if (s < 22) {
        // B[j][k] = sum_l W_ee[j,l] * W1[256+l, k]
        const int j = s - 19;
        float acc = 0.f;
        for (int l = 0; l < 128; ++l)
            acc += W_ee[j * 128 + l] * W1[(256 + l) * 128 + k];
        consts[k * 32 + s] = acc;
    } else if (s == 22) {
        // cvec[k] = b1[k] + b_en @ W1a[:,k] + g @ W1d[:,k]
        float acc = b1[k];
        for (int l = 0; l < 128; ++l)
            acc += b_en[l] * W1[l * 128 + k];
        for (int j = 0; j < 8; ++j)
            acc += g[j] * W1[(384 + j) * 128 + k];
        consts[k * 32 + 22] = acc;
    } else if (s == 23) {
        float acc = 0.f;
        for (int l = 0; l < 128; ++l)
            acc += b_ee[l] * W1[(128 + l) * 128 + k];
        consts[k * 32 + 23] = acc;
    } else if (s == 24) {
        float acc = 0.f;
        for (int l = 0; l < 128; ++l)
            acc += b_ee[l] * W1[(256 + l) * 128 + k];
        consts[k * 32 + 24] = acc;
    } else if (s == 25) {
        // w2dn[k] = sum_j W2[k,j] * W_dn[j]
        float acc = 0.f;
        for (int j = 0; j < 128; ++j)
            acc += W2[k * 128 + j] * W_dn[j];
        consts[k * 32 + 25] = acc;
        consts[k * 32 + 26] = 0.f;  // zero pads (loaded as part of float4, never used)
        consts[k * 32 + 27] = 0.f;
    } else {
        // s == 26: scalars
        if (k == 0) {
            float c = b_dn[0];
            for (int j = 0; j < 128; ++j) c += b2[j] * W_dn[j];
            scal[0] = c;
            float ce = b_de[0];
            for (int l = 0; l < 128; ++l) ce += b_ee[l] * W_de[l];
            scal[1] = ce;
            scal[5] = 0.f; scal[6] = 0.f; scal[7] = 0.f;
        }
        if (k < 3) {
            // wde3[j] = sum_l W_ee[j,l] * W_de[l]
            float acc = 0.f;
            for (int l = 0; l < 128; ++l)
                acc += W_ee[k * 128 + l] * W_de[l];
            scal[2 + k] = acc;
        }
    }
}

__global__ __launch_bounds__(256) void edge_kernel(
    const float* __restrict__ edges,     // [E][3]
    const int*   __restrict__ senders,   // [E]
    const int*   __restrict__ receivers, // [E]
    float* __restrict__ ws,
    float* __restrict__ out_edges)       // d_out + N_NODES
{
    const int e = blockIdx.x * 256 + threadIdx.x;
    if (e >= N_EDGES) return;
    const float e0 = edges[e * 3 + 0];
    const float e1 = edges[e * 3 + 1];
    const float e2 = edges[e * 3 + 2];
    const int s = senders[e];
    const int r = receivers[e];
    float* esr = ws + ESR_OFF;
    atomicAdd(&esr[s * 8 + 0], e0);
    atomicAdd(&esr[s * 8 + 1], e1);
    atomicAdd(&esr[s * 8 + 2], e2);
    atomicAdd(&esr[s * 8 + 3], 1.0f);
    atomicAdd(&esr[r * 8 + 4], e0);
    atomicAdd(&esr[r * 8 + 5], e1);
    atomicAdd(&esr[r * 8 + 6], e2);
    atomicAdd(&esr[r * 8 + 7], 1.0f);
    // fused edge decoder: edges_out = edges @ (W_ee@W_de) + (b_ee@W_de + b_de)
    const float* scal = ws + SCAL_OFF;
    out_edges[e] = e0 * scal[2] + e1 * scal[3] + e2 * scal[4] + scal[1];
}

__global__ __launch_bounds__(256) void node_kernel(
    const float* __restrict__ nodes,  // [N][16]
    const float* __restrict__ ws,
    float* __restrict__ out_nodes)    // d_out
{
    __shared__ float4 lds4[128 * 8];  // consts[128][32] as float4[128][8], 16 KiB
    const float4* consts4 = (const float4*)(ws + CONSTS_OFF);
    for (int i = threadIdx.x; i < 128 * 8; i += 256)
        lds4[i] = consts4[i];
    __syncthreads();

    const int n = blockIdx.x * 256 + threadIdx.x;
    if (n >= N_NODES) return;

    // node features (16 floats)
    const float4* np4 = (const float4*)(nodes + (size_t)n * 16);
    const float4 n0 = np4[0], n1 = np4[1], n2 = np4[2], n3 = np4[3];
    // aggregated edge sums + counts (8 floats)
    const float4* ep4 = (const float4*)(ws + ESR_OFF + (size_t)n * 8);
    const float4 es = ep4[0];  // es.x,es.y,es.z = sum sent edges; es.w = cnt_s
    const float4 er = ep4[1];  // er.x,er.y,er.z = sum recv edges; er.w = cnt_r

    float acc = 0.f;
#pragma unroll 4
    for (int k = 0; k < 128; ++k) {
        const float4* c4 = &lds4[k * 8];
        const float4 m0 = c4[0], m1 = c4[1], m2 = c4[2], m3 = c4[3];
        const float4 q0 = c4[4];  // A0 A1 A2 B0
        const float4 q1 = c4[5];  // B1 B2 cvec a0
        const float4 q2 = c4[6];  // b0 w2dn pad pad
        float pre = q1.z
            + n0.x * m0.x + n0.y * m0.y + n0.z * m0.z + n0.w * m0.w
            + n1.x * m1.x + n1.y * m1.y + n1.z * m1.z + n1.w * m1.w
            + n2.x * m2.x + n2.y * m2.y + n2.z * m2.z + n2.w * m2.w
            + n3.x * m3.x + n3.y * m3.y + n3.z * m3.z + n3.w * m3.w
            + es.x * q0.x + es.y * q0.y + es.z * q0.z
            + er.x * q0.w + er.y * q1.x + er.z * q1.y
            + es.w * q1.w + er.w * q2.x;
        acc += fmaxf(pre, 0.f) * q2.y;
    }
    const float* scal = ws + SCAL_OFF;
    out_nodes[n] = acc + scal[0];
}

extern "C" void kernel_launch(void* const* d_in, const int* in_sizes, int n_in,
                              void* d_out, int out_size, void* d_ws, size_t ws_size,
                              hipStream_t stream) {
    const float* nodes     = (const float*)d_in[0];
    const float* edges     = (const float*)d_in[1];
    const float* globals_  = (const float*)d_in[2];
    const int*   senders   = (const int*)d_in[3];
    const int*   receivers = (const int*)d_in[4];
    const float* W_en = (const float*)d_in[5];
    const float* b_en = (const float*)d_in[6];
    const float* W_ee = (const float*)d_in[7];
    const float* b_ee = (const float*)d_in[8];
    const float* W1   = (const float*)d_in[9];
    const float* b1   = (const float*)d_in[10];
    const float* W2   = (const float*)d_in[11];
    const float* b2   = (const float*)d_in[12];
    const float* W_dn = (const float*)d_in[13];
    const float* b_dn = (const float*)d_in[14];
    const float* W_de = (const float*)d_in[15];
    const float* b_de = (const float*)d_in[16];

    float* ws = (float*)d_ws;
    float* out = (float*)d_out;

    // zero the edge-aggregation accumulator (ws is poisoned each call)
    hipMemsetAsync(ws + ESR_OFF, 0, (size_t)N_NODES * 8 * sizeof(float), stream);

    precompute_kernel<<<27, 128, 0, stream>>>(
        globals_, W_en, b_en, W_ee, b_ee, W1, b1, W2, b2,
        W_dn, b_dn, W_de, b_de, ws);

    edge_kernel<<<(N_EDGES + 255) / 256, 256, 0, stream>>>(
        edges, senders, receivers, ws, out + N_NODES);

    node_kernel<<<(N_NODES + 255) / 256, 256, 0, stream>>>(
        nodes, ws, out);
}

// Round 2
// 244.846 us; speedup vs baseline: 1.8096x; 1.8096x over previous
//
#include <hip/hip_runtime.h>

#define N_NODES 50000
#define N_EDGES 800000

// ws layout (in floats):
//  [0, 400000)        esr[node][8] = {es0,es1,es2,cnt_s, er0,er1,er2,cnt_r}
//  [400000, 404096)   consts[k][32] (see precompute)
//  [404096, 404104)   scalars: {c, ce, wde0, wde1, wde2, pad...}
//  [404608, ...)      partial[c][node][8], c in [0, NCHUNKS)
#define ESR_OFF    0
#define CONSTS_OFF 400000
#define SCAL_OFF   404096
#define PART_OFF   404608

#define NBINS      25
#define BINSZ      2000   // nodes per bin; LDS = 2000*8*4 = 64000 B (2 blocks/CU)
#define MAX_CHUNKS 20

__global__ void precompute_kernel(
    const float* __restrict__ g,      // globals_ [8]
    const float* __restrict__ W_en,   // [16][128]
    const float* __restrict__ b_en,   // [128]
    const float* __restrict__ W_ee,   // [3][128]
    const float* __restrict__ b_ee,   // [128]
    const float* __restrict__ W1,     // [392][128]
    const float* __restrict__ b1,     // [128]
    const float* __restrict__ W2,     // [128][128]
    const float* __restrict__ b2,     // [128]
    const float* __restrict__ W_dn,   // [128]
    const float* __restrict__ b_dn,   // [1]
    const float* __restrict__ W_de,   // [128]
    const float* __restrict__ b_de,   // [1]
    float* __restrict__ ws)
{
    const int s = blockIdx.x;   // which slot/row we compute
    const int k = threadIdx.x;  // latent column 0..127
    float* consts = ws + CONSTS_OFF;
    float* scal   = ws + SCAL_OFF;

    if (s < 16) {
        float acc = 0.f;
        for (int l = 0; l < 128; ++l)
            acc += W_en[s * 128 + l] * W1[l * 128 + k];
        consts[k * 32 + s] = acc;
    } else if (s < 19) {
        const int j = s - 16;
        float acc = 0.f;
        for (int l = 0; l < 128; ++l)
            acc += W_ee[j * 128 + l] * W1[(128 + l) * 128 + k];
        consts[k * 32 + s] = acc;
    } else if (s < 22) {
        const int j = s - 19;
        float acc = 0.f;
        for (int l = 0; l < 128; ++l)
            acc += W_ee[j * 128 + l] * W1[(256 + l) * 128 + k];
        consts[k * 32 + s] = acc;
    } else if (s == 22) {
        float acc = b1[k];
        for (int l = 0; l < 128; ++l)
            acc += b_en[l] * W1[l * 128 + k];
        for (int j = 0; j < 8; ++j)
            acc += g[j] * W1[(384 + j) * 128 + k];
        consts[k * 32 + 22] = acc;
    } else if (s == 23) {
        float acc = 0.f;
        for (int l = 0; l < 128; ++l)
            acc += b_ee[l] * W1[(128 + l) * 128 + k];
        consts[k * 32 + 23] = acc;
    } else if (s == 24) {
        float acc = 0.f;
        for (int l = 0; l < 128; ++l)
            acc += b_ee[l] * W1[(256 + l) * 128 + k];
        consts[k * 32 + 24] = acc;
    } else if (s == 25) {
        float acc = 0.f;
        for (int j = 0; j < 128; ++j)
            acc += W2[k * 128 + j] * W_dn[j];
        consts[k * 32 + 25] = acc;
        consts[k * 32 + 26] = 0.f;
        consts[k * 32 + 27] = 0.f;
    } else {
        if (k == 0) {
            float c = b_dn[0];
            for (int j = 0; j < 128; ++j) c += b2[j] * W_dn[j];
            scal[0] = c;
            float ce = b_de[0];
            for (int l = 0; l < 128; ++l) ce += b_ee[l] * W_de[l];
            scal[1] = ce;
            scal[5] = 0.f; scal[6] = 0.f; scal[7] = 0.f;
        }
        if (k < 3) {
            float acc = 0.f;
            for (int l = 0; l < 128; ++l)
                acc += W_ee[k * 128 + l] * W_de[l];
            scal[2 + k] = acc;
        }
    }
}

// Binned aggregation: block (chunk=blockIdx.x, bin=blockIdx.y) scans edge
// range of its chunk, LDS-accumulates nodes within its bin, flushes the bin
// slice to partial[chunk] with plain stores. Bin-0 blocks also emit edges_out.
__global__ __launch_bounds__(256) void agg_kernel(
    const float* __restrict__ edges,     // [E][3]
    const int*   __restrict__ senders,   // [E]
    const int*   __restrict__ receivers, // [E]
    float* __restrict__ ws,
    float* __restrict__ out_edges,       // d_out + N_NODES
    int nchunks, int ce)                 // ce = edges per chunk
{
    __shared__ float4 acc4[BINSZ * 2];   // [BINSZ][8] floats = 64000 B
    float* acc = (float*)acc4;
    const int tid = threadIdx.x;
    for (int i = tid; i < BINSZ * 2; i += 256)
        acc4[i] = make_float4(0.f, 0.f, 0.f, 0.f);
    __syncthreads();

    const int chunk = blockIdx.x;
    const int bin   = blockIdx.y;
    const int lo    = bin * BINSZ;
    const bool isbin0 = (bin == 0);
    const float* scal = ws + SCAL_OFF;
    const float w0 = scal[2], w1 = scal[3], w2 = scal[4], ceb = scal[1];

    const int e_beg = chunk * ce;
    const int e_end = min(e_beg + ce, N_EDGES);
    for (int e = e_beg + tid; e < e_end; e += 256) {
        const int s = senders[e];
        const int r = receivers[e];
        const unsigned ds = (unsigned)(s - lo);
        const unsigned dr = (unsigned)(r - lo);
        const bool hs = ds < BINSZ;
        const bool hr = dr < BINSZ;
        if (hs | hr | isbin0) {
            const float e0 = edges[e * 3 + 0];
            const float e1 = edges[e * 3 + 1];
            const float e2 = edges[e * 3 + 2];
            if (isbin0)
                out_edges[e] = fmaf(e0, w0, fmaf(e1, w1, fmaf(e2, w2, ceb)));
            if (hs) {
                atomicAdd(&acc[ds * 8 + 0], e0);
                atomicAdd(&acc[ds * 8 + 1], e1);
                atomicAdd(&acc[ds * 8 + 2], e2);
                atomicAdd(&acc[ds * 8 + 3], 1.0f);
            }
            if (hr) {
                atomicAdd(&acc[dr * 8 + 4], e0);
                atomicAdd(&acc[dr * 8 + 5], e1);
                atomicAdd(&acc[dr * 8 + 6], e2);
                atomicAdd(&acc[dr * 8 + 7], 1.0f);
            }
        }
    }
    __syncthreads();

    // flush bin slice: partial[chunk][lo*8 .. lo*8 + BINSZ*8)
    float4* dst = (float4*)(ws + PART_OFF + (size_t)chunk * (N_NODES * 8) + (size_t)lo * 8);
    for (int i = tid; i < BINSZ * 2; i += 256)
        dst[i] = acc4[i];
}

__global__ __launch_bounds__(256) void reduce_kernel(
    float* __restrict__ ws, int nchunks)
{
    const int t = blockIdx.x * 256 + threadIdx.x;
    if (t >= N_NODES * 8) return;
    float a = 0.f;
    for (int c = 0; c < nchunks; ++c)
        a += ws[PART_OFF + (size_t)c * (N_NODES * 8) + t];
    ws[ESR_OFF + t] = a;
}

// ---- fallback path (small ws): original global-atomic scatter ----
__global__ __launch_bounds__(256) void edge_kernel_atomic(
    const float* __restrict__ edges,
    const int*   __restrict__ senders,
    const int*   __restrict__ receivers,
    float* __restrict__ ws,
    float* __restrict__ out_edges)
{
    const int e = blockIdx.x * 256 + threadIdx.x;
    if (e >= N_EDGES) return;
    const float e0 = edges[e * 3 + 0];
    const float e1 = edges[e * 3 + 1];
    const float e2 = edges[e * 3 + 2];
    const int s = senders[e];
    const int r = receivers[e];
    float* esr = ws + ESR_OFF;
    atomicAdd(&esr[s * 8 + 0], e0);
    atomicAdd(&esr[s * 8 + 1], e1);
    atomicAdd(&esr[s * 8 + 2], e2);
    atomicAdd(&esr[s * 8 + 3], 1.0f);
    atomicAdd(&esr[r * 8 + 4], e0);
    atomicAdd(&esr[r * 8 + 5], e1);
    atomicAdd(&esr[r * 8 + 6], e2);
    atomicAdd(&esr[r * 8 + 7], 1.0f);
    const float* scal = ws + SCAL_OFF;
    out_edges[e] = e0 * scal[2] + e1 * scal[3] + e2 * scal[4] + scal[1];
}

__global__ __launch_bounds__(256) void node_kernel(
    const float* __restrict__ nodes,  // [N][16]
    const float* __restrict__ ws,
    float* __restrict__ out_nodes)    // d_out
{
    __shared__ float4 lds4[128 * 8];  // consts[128][32] as float4[128][8], 16 KiB
    const float4* consts4 = (const float4*)(ws + CONSTS_OFF);
    for (int i = threadIdx.x; i < 128 * 8; i += 256)
        lds4[i] = consts4[i];
    __syncthreads();

    const int n = blockIdx.x * 256 + threadIdx.x;
    if (n >= N_NODES) return;

    const float4* np4 = (const float4*)(nodes + (size_t)n * 16);
    const float4 n0 = np4[0], n1 = np4[1], n2 = np4[2], n3 = np4[3];
    const float4* ep4 = (const float4*)(ws + ESR_OFF + (size_t)n * 8);
    const float4 es = ep4[0];
    const float4 er = ep4[1];

    float acc = 0.f;
#pragma unroll 4
    for (int k = 0; k < 128; ++k) {
        const float4* c4 = &lds4[k * 8];
        const float4 m0 = c4[0], m1 = c4[1], m2 = c4[2], m3 = c4[3];
        const float4 q0 = c4[4];
        const float4 q1 = c4[5];
        const float4 q2 = c4[6];
        float pre = q1.z
            + n0.x * m0.x + n0.y * m0.y + n0.z * m0.z + n0.w * m0.w
            + n1.x * m1.x + n1.y * m1.y + n1.z * m1.z + n1.w * m1.w
            + n2.x * m2.x + n2.y * m2.y + n2.z * m2.z + n2.w * m2.w
            + n3.x * m3.x + n3.y * m3.y + n3.z * m3.z + n3.w * m3.w
            + es.x * q0.x + es.y * q0.y + es.z * q0.z
            + er.x * q0.w + er.y * q1.x + er.z * q1.y
            + es.w * q1.w + er.w * q2.x;
        acc += fmaxf(pre, 0.f) * q2.y;
    }
    const float* scal = ws + SCAL_OFF;
    out_nodes[n] = acc + scal[0];
}

extern "C" void kernel_launch(void* const* d_in, const int* in_sizes, int n_in,
                              void* d_out, int out_size, void* d_ws, size_t ws_size,
                              hipStream_t stream) {
    const float* nodes     = (const float*)d_in[0];
    const float* edges     = (const float*)d_in[1];
    const float* globals_  = (const float*)d_in[2];
    const int*   senders   = (const int*)d_in[3];
    const int*   receivers = (const int*)d_in[4];
    const float* W_en = (const float*)d_in[5];
    const float* b_en = (const float*)d_in[6];
    const float* W_ee = (const float*)d_in[7];
    const float* b_ee = (const float*)d_in[8];
    const float* W1   = (const float*)d_in[9];
    const float* b1   = (const float*)d_in[10];
    const float* W2   = (const float*)d_in[11];
    const float* b2   = (const float*)d_in[12];
    const float* W_dn = (const float*)d_in[13];
    const float* b_dn = (const float*)d_in[14];
    const float* W_de = (const float*)d_in[15];
    const float* b_de = (const float*)d_in[16];

    float* ws = (float*)d_ws;
    float* out = (float*)d_out;

    precompute_kernel<<<27, 128, 0, stream>>>(
        globals_, W_en, b_en, W_ee, b_ee, W1, b1, W2, b2,
        W_dn, b_dn, W_de, b_de, ws);

    // how many partial-sum copies fit in ws?
    long ws_floats = (long)(ws_size / 4);
    long avail = (ws_floats - PART_OFF) / (N_NODES * 8);
    int nchunks = (int)(avail < 0 ? 0 : (avail > MAX_CHUNKS ? MAX_CHUNKS : avail));

    if (nchunks >= 1) {
        const int ce = (N_EDGES + nchunks - 1) / nchunks;
        dim3 grid(nchunks, NBINS);
        agg_kernel<<<grid, 256, 0, stream>>>(
            edges, senders, receivers, ws, out + N_NODES, nchunks, ce);
        reduce_kernel<<<(N_NODES * 8 + 255) / 256, 256, 0, stream>>>(ws, nchunks);
    } else {
        hipMemsetAsync(ws + ESR_OFF, 0, (size_t)N_NODES * 8 * sizeof(float), stream);
        edge_kernel_atomic<<<(N_EDGES + 255) / 256, 256, 0, stream>>>(
            edges, senders, receivers, ws, out + N_NODES);
    }

    node_kernel<<<(N_NODES + 255) / 256, 256, 0, stream>>>(
        nodes, ws, out);
}

// Round 3
// 175.132 us; speedup vs baseline: 2.5300x; 1.3981x over previous
//
#include <hip/hip_runtime.h>

#define N_NODES 50000
#define N_EDGES 800000

// ws layout (in floats):
//  [0, 400000)        esr[node][8] (fallback path only)
//  [400000, 404096)   consts[k][32] (see precompute)
//  [404096, 404104)   scalars: {c, ce, wde0, wde1, wde2, pad...}
//  [404608, ...)      partial[c][node][8], c in [0, NCHUNKS)
#define ESR_OFF    0
#define CONSTS_OFF 400000
#define SCAL_OFF   404096
#define PART_OFF   404608

#define NBINS      25
#define BINSZ      2000   // nodes per bin; LDS = 2000*8*4 = 64000 B; 2 blocks/CU
#define MAX_CHUNKS 20

__global__ void precompute_kernel(
    const float* __restrict__ g,      // globals_ [8]
    const float* __restrict__ W_en,   // [16][128]
    const float* __restrict__ b_en,   // [128]
    const float* __restrict__ W_ee,   // [3][128]
    const float* __restrict__ b_ee,   // [128]
    const float* __restrict__ W1,     // [392][128]
    const float* __restrict__ b1,     // [128]
    const float* __restrict__ W2,     // [128][128]
    const float* __restrict__ b2,     // [128]
    const float* __restrict__ W_dn,   // [128]
    const float* __restrict__ b_dn,   // [1]
    const float* __restrict__ W_de,   // [128]
    const float* __restrict__ b_de,   // [1]
    float* __restrict__ ws)
{
    const int s = blockIdx.x;
    const int k = threadIdx.x;
    float* consts = ws + CONSTS_OFF;
    float* scal   = ws + SCAL_OFF;

    if (s < 16) {
        float acc = 0.f;
        for (int l = 0; l < 128; ++l)
            acc += W_en[s * 128 + l] * W1[l * 128 + k];
        consts[k * 32 + s] = acc;
    } else if (s < 19) {
        const int j = s - 16;
        float acc = 0.f;
        for (int l = 0; l < 128; ++l)
            acc += W_ee[j * 128 + l] * W1[(128 + l) * 128 + k];
        consts[k * 32 + s] = acc;
    } else if (s < 22) {
        const int j = s - 19;
        float acc = 0.f;
        for (int l = 0; l < 128; ++l)
            acc += W_ee[j * 128 + l] * W1[(256 + l) * 128 + k];
        consts[k * 32 + s] = acc;
    } else if (s == 22) {
        float acc = b1[k];
        for (int l = 0; l < 128; ++l)
            acc += b_en[l] * W1[l * 128 + k];
        for (int j = 0; j < 8; ++j)
            acc += g[j] * W1[(384 + j) * 128 + k];
        consts[k * 32 + 22] = acc;
    } else if (s == 23) {
        float acc = 0.f;
        for (int l = 0; l < 128; ++l)
            acc += b_ee[l] * W1[(128 + l) * 128 + k];
        consts[k * 32 + 23] = acc;
    } else if (s == 24) {
        float acc = 0.f;
        for (int l = 0; l < 128; ++l)
            acc += b_ee[l] * W1[(256 + l) * 128 + k];
        consts[k * 32 + 24] = acc;
    } else if (s == 25) {
        float acc = 0.f;
        for (int j = 0; j < 128; ++j)
            acc += W2[k * 128 + j] * W_dn[j];
        consts[k * 32 + 25] = acc;
        consts[k * 32 + 26] = 0.f;
        consts[k * 32 + 27] = 0.f;
    } else {
        if (k == 0) {
            float c = b_dn[0];
            for (int j = 0; j < 128; ++j) c += b2[j] * W_dn[j];
            scal[0] = c;
            float ce = b_de[0];
            for (int l = 0; l < 128; ++l) ce += b_ee[l] * W_de[l];
            scal[1] = ce;
            scal[5] = 0.f; scal[6] = 0.f; scal[7] = 0.f;
        }
        if (k < 3) {
            float acc = 0.f;
            for (int l = 0; l < 128; ++l)
                acc += W_ee[k * 128 + l] * W_de[l];
            scal[2 + k] = acc;
        }
    }
}

// Pure streaming edge decoder: edges_out = edges @ (W_ee@W_de) + (b_ee@W_de + b_de)
__global__ __launch_bounds__(256) void edge_out_kernel(
    const float* __restrict__ edges,
    const float* __restrict__ ws,
    float* __restrict__ out_edges)
{
    const int e4 = (blockIdx.x * 256 + threadIdx.x) * 4;
    if (e4 >= N_EDGES) return;
    const float* scal = ws + SCAL_OFF;
    const float w0 = scal[2], w1 = scal[3], w2 = scal[4], cb = scal[1];
    const float4* ep = (const float4*)(edges + (size_t)e4 * 3);
    const float4 f0 = ep[0], f1 = ep[1], f2 = ep[2];
    float4 o;
    o.x = fmaf(f0.x, w0, fmaf(f0.y, w1, fmaf(f0.z, w2, cb)));
    o.y = fmaf(f0.w, w0, fmaf(f1.x, w1, fmaf(f1.y, w2, cb)));
    o.z = fmaf(f1.z, w0, fmaf(f1.w, w1, fmaf(f2.x, w2, cb)));
    o.w = fmaf(f2.y, w0, fmaf(f2.z, w1, fmaf(f2.w, w2, cb)));
    *(float4*)(out_edges + e4) = o;
}

// Binned aggregation, 4 edges/thread, 512-thread blocks (16 waves/CU at 64KB LDS).
__global__ __launch_bounds__(512) void agg_kernel(
    const float* __restrict__ edges,     // [E][3]
    const int*   __restrict__ senders,   // [E]
    const int*   __restrict__ receivers, // [E]
    float* __restrict__ ws,
    int ce)                              // edges per chunk (multiple of 4)
{
    __shared__ float4 acc4[BINSZ * 2];   // [BINSZ][8] floats = 64000 B
    float* acc = (float*)acc4;
    const int tid = threadIdx.x;
    for (int i = tid; i < BINSZ * 2; i += 512)
        acc4[i] = make_float4(0.f, 0.f, 0.f, 0.f);
    __syncthreads();

    const int chunk = blockIdx.x;
    const int bin   = blockIdx.y;
    const int lo    = bin * BINSZ;

    const int e_beg = chunk * ce;
    const int e_end = min(e_beg + ce, N_EDGES);
    for (int e4 = e_beg + tid * 4; e4 < e_end; e4 += 512 * 4) {
        const int4 s4 = *(const int4*)(senders + e4);
        const int4 r4 = *(const int4*)(receivers + e4);
        const unsigned ds0 = (unsigned)(s4.x - lo), ds1 = (unsigned)(s4.y - lo);
        const unsigned ds2 = (unsigned)(s4.z - lo), ds3 = (unsigned)(s4.w - lo);
        const unsigned dr0 = (unsigned)(r4.x - lo), dr1 = (unsigned)(r4.y - lo);
        const unsigned dr2 = (unsigned)(r4.z - lo), dr3 = (unsigned)(r4.w - lo);
        const bool h = (ds0 < BINSZ) | (ds1 < BINSZ) | (ds2 < BINSZ) | (ds3 < BINSZ) |
                       (dr0 < BINSZ) | (dr1 < BINSZ) | (dr2 < BINSZ) | (dr3 < BINSZ);
        if (!h) continue;
        const float4* ep = (const float4*)(edges + (size_t)e4 * 3);
        const float4 f0 = ep[0], f1 = ep[1], f2 = ep[2];
        // edge0: f0.x f0.y f0.z | edge1: f0.w f1.x f1.y | edge2: f1.z f1.w f2.x | edge3: f2.y f2.z f2.w
        if (ds0 < BINSZ) {
            atomicAdd(&acc[ds0 * 8 + 0], f0.x); atomicAdd(&acc[ds0 * 8 + 1], f0.y);
            atomicAdd(&acc[ds0 * 8 + 2], f0.z); atomicAdd(&acc[ds0 * 8 + 3], 1.0f);
        }
        if (dr0 < BINSZ) {
            atomicAdd(&acc[dr0 * 8 + 4], f0.x); atomicAdd(&acc[dr0 * 8 + 5], f0.y);
            atomicAdd(&acc[dr0 * 8 + 6], f0.z); atomicAdd(&acc[dr0 * 8 + 7], 1.0f);
        }
        if (ds1 < BINSZ) {
            atomicAdd(&acc[ds1 * 8 + 0], f0.w); atomicAdd(&acc[ds1 * 8 + 1], f1.x);
            atomicAdd(&acc[ds1 * 8 + 2], f1.y); atomicAdd(&acc[ds1 * 8 + 3], 1.0f);
        }
        if (dr1 < BINSZ) {
            atomicAdd(&acc[dr1 * 8 + 4], f0.w); atomicAdd(&acc[dr1 * 8 + 5], f1.x);
            atomicAdd(&acc[dr1 * 8 + 6], f1.y); atomicAdd(&acc[dr1 * 8 + 7], 1.0f);
        }
        if (ds2 < BINSZ) {
            atomicAdd(&acc[ds2 * 8 + 0], f1.z); atomicAdd(&acc[ds2 * 8 + 1], f1.w);
            atomicAdd(&acc[ds2 * 8 + 2], f2.x); atomicAdd(&acc[ds2 * 8 + 3], 1.0f);
        }
        if (dr2 < BINSZ) {
            atomicAdd(&acc[dr2 * 8 + 4], f1.z); atomicAdd(&acc[dr2 * 8 + 5], f1.w);
            atomicAdd(&acc[dr2 * 8 + 6], f2.x); atomicAdd(&acc[dr2 * 8 + 7], 1.0f);
        }
        if (ds3 < BINSZ) {
            atomicAdd(&acc[ds3 * 8 + 0], f2.y); atomicAdd(&acc[ds3 * 8 + 1], f2.z);
            atomicAdd(&acc[ds3 * 8 + 2], f2.w); atomicAdd(&acc[ds3 * 8 + 3], 1.0f);
        }
        if (dr3 < BINSZ) {
            atomicAdd(&acc[dr3 * 8 + 4], f2.y); atomicAdd(&acc[dr3 * 8 + 5], f2.z);
            atomicAdd(&acc[dr3 * 8 + 6], f2.w); atomicAdd(&acc[dr3 * 8 + 7], 1.0f);
        }
    }
    __syncthreads();

    float4* dst = (float4*)(ws + PART_OFF + (size_t)chunk * (N_NODES * 8) + (size_t)lo * 8);
    for (int i = tid; i < BINSZ * 2; i += 512)
        dst[i] = acc4[i];
}

// ---- fallback path (tiny ws): global-atomic scatter into esr ----
__global__ __launch_bounds__(256) void edge_kernel_atomic(
    const float* __restrict__ edges,
    const int*   __restrict__ senders,
    const int*   __restrict__ receivers,
    float* __restrict__ ws)
{
    const int e = blockIdx.x * 256 + threadIdx.x;
    if (e >= N_EDGES) return;
    const float e0 = edges[e * 3 + 0];
    const float e1 = edges[e * 3 + 1];
    const float e2 = edges[e * 3 + 2];
    const int s = senders[e];
    const int r = receivers[e];
    float* esr = ws + ESR_OFF;
    atomicAdd(&esr[s * 8 + 0], e0);
    atomicAdd(&esr[s * 8 + 1], e1);
    atomicAdd(&esr[s * 8 + 2], e2);
    atomicAdd(&esr[s * 8 + 3], 1.0f);
    atomicAdd(&esr[r * 8 + 4], e0);
    atomicAdd(&esr[r * 8 + 5], e1);
    atomicAdd(&esr[r * 8 + 6], e2);
    atomicAdd(&esr[r * 8 + 7], 1.0f);
}

// Node MLP; nchunks>0: inline-reduce the partial copies, else read esr.
__global__ __launch_bounds__(256) void node_kernel(
    const float* __restrict__ nodes,  // [N][16]
    const float* __restrict__ ws,
    float* __restrict__ out_nodes,    // d_out
    int nchunks)
{
    __shared__ float4 lds4[128 * 8];  // consts[128][32] as float4[128][8], 16 KiB
    const float4* consts4 = (const float4*)(ws + CONSTS_OFF);
    for (int i = threadIdx.x; i < 128 * 8; i += 256)
        lds4[i] = consts4[i];
    __syncthreads();

    const int n = blockIdx.x * 256 + threadIdx.x;
    if (n >= N_NODES) return;

    const float4* np4 = (const float4*)(nodes + (size_t)n * 16);
    const float4 n0 = np4[0], n1 = np4[1], n2 = np4[2], n3 = np4[3];

    float4 es = make_float4(0.f, 0.f, 0.f, 0.f);
    float4 er = make_float4(0.f, 0.f, 0.f, 0.f);
    if (nchunks > 0) {
        for (int c = 0; c < nchunks; ++c) {
            const float4* p = (const float4*)(ws + PART_OFF + (size_t)c * (N_NODES * 8) + (size_t)n * 8);
            const float4 a = p[0], b = p[1];
            es.x += a.x; es.y += a.y; es.z += a.z; es.w += a.w;
            er.x += b.x; er.y += b.y; er.z += b.z; er.w += b.w;
        }
    } else {
        const float4* p = (const float4*)(ws + ESR_OFF + (size_t)n * 8);
        es = p[0];
        er = p[1];
    }

    float acc = 0.f;
#pragma unroll 4
    for (int k = 0; k < 128; ++k) {
        const float4* c4 = &lds4[k * 8];
        const float4 m0 = c4[0], m1 = c4[1], m2 = c4[2], m3 = c4[3];
        const float4 q0 = c4[4];
        const float4 q1 = c4[5];
        const float4 q2 = c4[6];
        float pre = q1.z
            + n0.x * m0.x + n0.y * m0.y + n0.z * m0.z + n0.w * m0.w
            + n1.x * m1.x + n1.y * m1.y + n1.z * m1.z + n1.w * m1.w
            + n2.x * m2.x + n2.y * m2.y + n2.z * m2.z + n2.w * m2.w
            + n3.x * m3.x + n3.y * m3.y + n3.z * m3.z + n3.w * m3.w
            + es.x * q0.x + es.y * q0.y + es.z * q0.z
            + er.x * q0.w + er.y * q1.x + er.z * q1.y
            + es.w * q1.w + er.w * q2.x;
        acc += fmaxf(pre, 0.f) * q2.y;
    }
    const float* scal = ws + SCAL_OFF;
    out_nodes[n] = acc + scal[0];
}

extern "C" void kernel_launch(void* const* d_in, const int* in_sizes, int n_in,
                              void* d_out, int out_size, void* d_ws, size_t ws_size,
                              hipStream_t stream) {
    const float* nodes     = (const float*)d_in[0];
    const float* edges     = (const float*)d_in[1];
    const float* globals_  = (const float*)d_in[2];
    const int*   senders   = (const int*)d_in[3];
    const int*   receivers = (const int*)d_in[4];
    const float* W_en = (const float*)d_in[5];
    const float* b_en = (const float*)d_in[6];
    const float* W_ee = (const float*)d_in[7];
    const float* b_ee = (const float*)d_in[8];
    const float* W1   = (const float*)d_in[9];
    const float* b1   = (const float*)d_in[10];
    const float* W2   = (const float*)d_in[11];
    const float* b2   = (const float*)d_in[12];
    const float* W_dn = (const float*)d_in[13];
    const float* b_dn = (const float*)d_in[14];
    const float* W_de = (const float*)d_in[15];
    const float* b_de = (const float*)d_in[16];

    float* ws = (float*)d_ws;
    float* out = (float*)d_out;

    precompute_kernel<<<27, 128, 0, stream>>>(
        globals_, W_en, b_en, W_ee, b_ee, W1, b1, W2, b2,
        W_dn, b_dn, W_de, b_de, ws);

    edge_out_kernel<<<(N_EDGES / 4 + 255) / 256, 256, 0, stream>>>(
        edges, ws, out + N_NODES);

    long ws_floats = (long)(ws_size / 4);
    long avail = (ws_floats - PART_OFF) / (N_NODES * 8);
    int nchunks = (int)(avail < 0 ? 0 : (avail > MAX_CHUNKS ? MAX_CHUNKS : avail));

    if (nchunks >= 1) {
        int ce = (N_EDGES + nchunks - 1) / nchunks;
        ce = (ce + 3) & ~3;  // keep quads aligned
        dim3 grid(nchunks, NBINS);
        agg_kernel<<<grid, 512, 0, stream>>>(edges, senders, receivers, ws, ce);
    } else {
        hipMemsetAsync(ws + ESR_OFF, 0, (size_t)N_NODES * 8 * sizeof(float), stream);
        edge_kernel_atomic<<<(N_EDGES + 255) / 256, 256, 0, stream>>>(
            edges, senders, receivers, ws);
    }

    node_kernel<<<(N_NODES + 255) / 256, 256, 0, stream>>>(
        nodes, ws, out, nchunks);
}